// Round 1
// baseline (864.674 us; speedup 1.0000x reference)
//
#include <hip/hip_runtime.h>

#define HWL   32
#define SPAT  32768          // 32*32*32
#define C_IN  64
#define C_OUT 64
#define KPROD 27
#define TILE_P 64            // output positions per block (two L-rows)

__global__ __launch_bounds__(256, 2)
void dconv3d_fused(const float* __restrict__ x,
                   const float* __restrict__ offset,
                   const float* __restrict__ mask,
                   const float* __restrict__ weight,
                   float* __restrict__ out) {
    __shared__ float W_lds[C_IN * C_OUT];        // [c][o], 16 KB
    __shared__ float cols_lds[C_IN * TILE_P];    // [c][p], 16 KB
    __shared__ float wgt_lds[8][TILE_P];         // 2 KB
    __shared__ int   lin_lds[8][TILE_P];         // 2 KB

    const int t = threadIdx.x;
    const int p_base = blockIdx.x * TILE_P;

    const int o    = t & 63;   // GEMM role: output channel
    const int pg   = t >> 6;   // GEMM role: position group (16 positions)
    const int p_s  = t & 63;   // sampling role: position
    const int cgrp = t >> 6;   // sampling role: channel group (16 channels)

    float acc[16];
#pragma unroll
    for (int i = 0; i < 16; ++i) acc[i] = 0.f;

    for (int k = 0; k < KPROD; ++k) {
        // ---- stage W_k into LDS as [c][o] (stride-1 writes) ----
#pragma unroll
        for (int i = 0; i < 16; ++i) {
            int idx = i * 256 + t;
            int c = idx >> 6, oo = idx & 63;
            W_lds[idx] = weight[(oo * C_IN + c) * KPROD + k];
        }
        // ---- precompute trilinear corner weights + clamped indices ----
        if (t < TILE_P) {
            int pos = p_base + t;
            int ho = pos >> 10, wo = (pos >> 5) & 31, lo = pos & 31;
            int ki = k / 9, kj = (k / 3) % 3, kk = k % 3;
            float chh = offset[(3 * k + 0) * SPAT + pos] + (float)(ho - 1 + ki);
            float cww = offset[(3 * k + 1) * SPAT + pos] + (float)(wo - 1 + kj);
            float cll = offset[(3 * k + 2) * SPAT + pos] + (float)(lo - 1 + kk);
            float m = mask[k * SPAT + pos];
            float h0f = floorf(chh), w0f = floorf(cww), l0f = floorf(cll);
            float fh = chh - h0f, fw = cww - w0f, fl = cll - l0f;
            int h0 = (int)h0f, w0 = (int)w0f, l0 = (int)l0f;
#pragma unroll
            for (int j = 0; j < 8; ++j) {
                int dh = j >> 2, dw = (j >> 1) & 1, dl = j & 1;
                int ih = h0 + dh, iw = w0 + dw, il = l0 + dl;
                float wh = dh ? fh : 1.f - fh;
                float ww = dw ? fw : 1.f - fw;
                float wl = dl ? fl : 1.f - fl;
                bool valid = (unsigned)ih < 32u && (unsigned)iw < 32u && (unsigned)il < 32u;
                float wv = valid ? wh * ww * wl * m : 0.f;
                int ihc = min(max(ih, 0), 31);
                int iwc = min(max(iw, 0), 31);
                int ilc = min(max(il, 0), 31);
                wgt_lds[j][t] = wv;
                lin_lds[j][t] = (ihc * 32 + iwc) * 32 + ilc;
            }
        }
        __syncthreads();

        // ---- sampling: build cols[c][p] for 16 channels per thread ----
        float wreg[8]; int lreg[8];
#pragma unroll
        for (int j = 0; j < 8; ++j) { wreg[j] = wgt_lds[j][p_s]; lreg[j] = lin_lds[j][p_s]; }
#pragma unroll 4
        for (int cc = 0; cc < 16; ++cc) {
            int c = cgrp * 16 + cc;
            const float* xc = x + c * SPAT;
            float v = 0.f;
#pragma unroll
            for (int j = 0; j < 8; ++j) v = fmaf(wreg[j], xc[lreg[j]], v);
            cols_lds[c * TILE_P + p_s] = v;
        }
        __syncthreads();

        // ---- rank-64 update: acc[o][pg*16 + i] += W[c][o] * cols[c][p] ----
        const float* colp = &cols_lds[pg * 16];
#pragma unroll 4
        for (int c = 0; c < C_IN; ++c) {
            float w = W_lds[c * 64 + o];
#pragma unroll
            for (int i = 0; i < 16; ++i)
                acc[i] = fmaf(w, colp[c * TILE_P + i], acc[i]);
        }
        __syncthreads();
    }

    // ---- coalesced store via LDS transpose (reuse cols_lds) ----
    float* stash = cols_lds;
#pragma unroll
    for (int i = 0; i < 16; ++i)
        stash[o * TILE_P + pg * 16 + i] = acc[i];
    __syncthreads();
#pragma unroll
    for (int it = 0; it < 16; ++it) {
        int idx = it * 256 + t;
        int oo = idx >> 6, pp = idx & 63;
        out[oo * SPAT + p_base + pp] = stash[idx];
    }
}

extern "C" void kernel_launch(void* const* d_in, const int* in_sizes, int n_in,
                              void* d_out, int out_size, void* d_ws, size_t ws_size,
                              hipStream_t stream) {
    const float* x      = (const float*)d_in[0];
    const float* offset = (const float*)d_in[1];
    const float* mask   = (const float*)d_in[2];
    const float* weight = (const float*)d_in[3];
    float* out = (float*)d_out;

    dim3 grid(SPAT / TILE_P);   // 512 blocks
    dim3 block(256);
    hipLaunchKernelGGL(dconv3d_fused, grid, block, 0, stream,
                       x, offset, mask, weight, out);
}

// Round 2
// 135.675 us; speedup vs baseline: 6.3731x; 6.3731x over previous
//
#include <hip/hip_runtime.h>
#include <hip/hip_bf16.h>

typedef short short8 __attribute__((ext_vector_type(8)));
typedef float f32x4 __attribute__((ext_vector_type(4)));
typedef float f32x2 __attribute__((ext_vector_type(2)));

#define SPAT  32768
#define C_IN  64
#define C_OUT 64
#define KPROD 27
#define TILE_P 64

static __device__ __forceinline__ short f2bf(float f) {
    return (short)__bfloat16_as_ushort(__float2bfloat16(f));
}

// ---- prep 1: transpose x [64][32768] f32 -> xt [32768][64] f32 ----
__global__ void transpose_x(const float* __restrict__ x, float* __restrict__ xt) {
    __shared__ float tile[64][65];
    const int t = threadIdx.x;
    const int s0 = blockIdx.x * 64;
    const int lane = t & 63, grp = t >> 6;
#pragma unroll
    for (int r = 0; r < 16; ++r) {
        int c = grp * 16 + r;
        tile[c][lane] = x[c * SPAT + s0 + lane];
    }
    __syncthreads();
#pragma unroll
    for (int r = 0; r < 16; ++r) {
        int srow = grp * 16 + r;
        xt[(s0 + srow) * 64 + lane] = tile[lane][srow];
    }
}

// ---- prep 2: weight [o][c][k] f32 -> wt [k][o*64+c] bf16 ----
__global__ void prep_w(const float* __restrict__ w, unsigned short* __restrict__ wt) {
    int idx = blockIdx.x * 256 + threadIdx.x;   // 27*4096 total
    if (idx >= KPROD * 4096) return;
    int k = idx >> 12, oc = idx & 4095;         // oc = o*64 + c
    wt[idx] = __bfloat16_as_ushort(__float2bfloat16(w[oc * KPROD + k]));
}

// ---- main: fused sampling + bf16-MFMA implicit GEMM ----
__global__ __launch_bounds__(256, 2)
void dconv3d_mfma(const float* __restrict__ xt, const unsigned short* __restrict__ wt,
                  const float* __restrict__ offset, const float* __restrict__ mask,
                  float* __restrict__ out) {
    __shared__ short W_lds[4096];      // [o][c] bf16, 8-elem XOR swizzle: cb^(o&7)
    __shared__ float cols_lds[4096];   // [p][c] f32, quad XOR swizzle: cq^(p&15)
    __shared__ float meta[64 * 16];    // [p][j][{w, byte_off}]

    const int t = threadIdx.x;
    const int p_base = blockIdx.x * TILE_P;
    const int lane = t & 63;
    const int wv = t >> 6;

    f32x4 acc[4] = {};

    const int cq = t & 15;        // sampling: channel quad
    const int pg = t >> 4;        // sampling: p group (4 p each)
    const int mj = wv * 2;        // meta: corner pair

    for (int k = 0; k < KPROD; ++k) {
        // ---- stage W_k into LDS (coalesced b128 reads, swizzled writes) ----
        {
            const unsigned short* src = wt + k * 4096 + t * 16;
            short8 w0 = *(const short8*)(src);
            short8 w1 = *(const short8*)(src + 8);
            int o = t >> 2;
            int cb0 = (t & 3) * 2;
            *(short8*)&W_lds[o * 64 + ((cb0 ^ (o & 7)) << 3)] = w0;
            *(short8*)&W_lds[o * 64 + (((cb0 + 1) ^ (o & 7)) << 3)] = w1;
        }
        // ---- meta: trilinear weights + byte offsets (corner-parallel) ----
        {
            const int p = lane;
            const int pos = p_base + p;
            const int ho = pos >> 10, wo = (pos >> 5) & 31, lo = pos & 31;
            const int ki = k / 9, kj = (k / 3) % 3, kk = k % 3;
            float chh = offset[(3 * k + 0) * SPAT + pos] + (float)(ho - 1 + ki);
            float cww = offset[(3 * k + 1) * SPAT + pos] + (float)(wo - 1 + kj);
            float cll = offset[(3 * k + 2) * SPAT + pos] + (float)(lo - 1 + kk);
            const float m = mask[k * SPAT + pos];
            float h0f = floorf(chh), w0f = floorf(cww), l0f = floorf(cll);
            float fh = chh - h0f, fw = cww - w0f, fl = cll - l0f;
            int h0 = (int)h0f, w0 = (int)w0f, l0 = (int)l0f;
#pragma unroll
            for (int jj = 0; jj < 2; ++jj) {
                int j = mj + jj;
                int dh = j >> 2, dw = (j >> 1) & 1, dl = j & 1;
                int ih = h0 + dh, iw = w0 + dw, il = l0 + dl;
                float wh = dh ? fh : 1.f - fh;
                float ww = dw ? fw : 1.f - fw;
                float wl = dl ? fl : 1.f - fl;
                bool valid = (unsigned)ih < 32u && (unsigned)iw < 32u && (unsigned)il < 32u;
                float wvv = valid ? wh * ww * wl * m : 0.f;
                int ihc = min(max(ih, 0), 31);
                int iwc = min(max(iw, 0), 31);
                int ilc = min(max(il, 0), 31);
                int lin = (ihc * 32 + iwc) * 32 + ilc;
                meta[p * 16 + j * 2]     = wvv;
                meta[p * 16 + j * 2 + 1] = __int_as_float(lin * 256);  // byte offset into xt row
            }
        }
        __syncthreads();

        // ---- sampling: coalesced dwordx4 channel-quad gathers -> cols[p][c] ----
        {
            const char* xbase = (const char*)xt + cq * 16;
#pragma unroll
            for (int i = 0; i < 4; ++i) {
                int p = pg * 4 + i;
                f32x4 v = {0.f, 0.f, 0.f, 0.f};
#pragma unroll
                for (int j = 0; j < 8; ++j) {
                    f32x2 md = *(const f32x2*)&meta[p * 16 + j * 2];
                    const f32x4 xr = *(const f32x4*)(xbase + __float_as_int(md.y));
                    v.x = fmaf(md.x, xr.x, v.x);
                    v.y = fmaf(md.x, xr.y, v.y);
                    v.z = fmaf(md.x, xr.z, v.z);
                    v.w = fmaf(md.x, xr.w, v.w);
                }
                *(f32x4*)&cols_lds[p * 64 + ((cq ^ (p & 15)) << 2)] = v;
            }
        }
        __syncthreads();

        // ---- MFMA: D[64o x 16p per wave] += W_k * cols_k ----
        {
            const int m_ = lane & 15, g = lane >> 4;
            const int p = wv * 16 + m_;
            short8 b[2];
#pragma unroll
            for (int kb = 0; kb < 2; ++kb) {
                int cq0 = kb * 8 + g * 2;
                f32x4 x0 = *(const f32x4*)&cols_lds[p * 64 + ((cq0 ^ (p & 15)) << 2)];
                f32x4 x1 = *(const f32x4*)&cols_lds[p * 64 + (((cq0 + 1) ^ (p & 15)) << 2)];
                b[kb] = short8{f2bf(x0.x), f2bf(x0.y), f2bf(x0.z), f2bf(x0.w),
                               f2bf(x1.x), f2bf(x1.y), f2bf(x1.z), f2bf(x1.w)};
            }
#pragma unroll
            for (int ot = 0; ot < 4; ++ot) {
                int o = ot * 16 + m_;
                short8 a0 = *(const short8*)&W_lds[o * 64 + ((g ^ (o & 7)) << 3)];
                short8 a1 = *(const short8*)&W_lds[o * 64 + (((4 + g) ^ (o & 7)) << 3)];
                acc[ot] = __builtin_amdgcn_mfma_f32_16x16x32_bf16(a0, b[0], acc[ot], 0, 0, 0);
                acc[ot] = __builtin_amdgcn_mfma_f32_16x16x32_bf16(a1, b[1], acc[ot], 0, 0, 0);
            }
        }
        __syncthreads();
    }

    // ---- store: D col=lane&15 (p), row=(lane>>4)*4+r (o) ----
    {
        const int m_ = lane & 15, g = lane >> 4;
        const int p = p_base + wv * 16 + m_;
#pragma unroll
        for (int ot = 0; ot < 4; ++ot)
#pragma unroll
            for (int r = 0; r < 4; ++r) {
                int o = ot * 16 + g * 4 + r;
                out[o * SPAT + p] = acc[ot][r];
            }
    }
}

extern "C" void kernel_launch(void* const* d_in, const int* in_sizes, int n_in,
                              void* d_out, int out_size, void* d_ws, size_t ws_size,
                              hipStream_t stream) {
    const float* x      = (const float*)d_in[0];
    const float* offset = (const float*)d_in[1];
    const float* mask   = (const float*)d_in[2];
    const float* weight = (const float*)d_in[3];
    float* out = (float*)d_out;

    float* xt = (float*)d_ws;                                      // 8 MB
    unsigned short* wtb = (unsigned short*)((char*)d_ws + (size_t)SPAT * 64 * 4); // 216 KB

    hipLaunchKernelGGL(transpose_x, dim3(SPAT / 64), dim3(256), 0, stream, x, xt);
    hipLaunchKernelGGL(prep_w, dim3((KPROD * 4096 + 255) / 256), dim3(256), 0, stream,
                       weight, wtb);
    hipLaunchKernelGGL(dconv3d_mfma, dim3(SPAT / TILE_P), dim3(256), 0, stream,
                       xt, wtb, offset, mask, out);
}

// Round 3
// 125.581 us; speedup vs baseline: 6.8854x; 1.0804x over previous
//
#include <hip/hip_runtime.h>
#include <hip/hip_bf16.h>

typedef short short8 __attribute__((ext_vector_type(8)));
typedef unsigned int u32x4 __attribute__((ext_vector_type(4)));
typedef float f32x4 __attribute__((ext_vector_type(4)));

#define SPAT  32768
#define KPROD 27

// ---- prep 1: x [64][32768] f32 -> xt [32768][64] bf16 (128B rows) ----
__global__ void transpose_x_bf16(const float* __restrict__ x, unsigned short* __restrict__ xt) {
    __shared__ float tile[64][65];
    const int t = threadIdx.x;
    const int s0 = blockIdx.x * 64;
    const int lane = t & 63, grp = t >> 6;
#pragma unroll
    for (int r = 0; r < 16; ++r) {
        int c = grp * 16 + r;
        tile[c][lane] = x[c * SPAT + s0 + lane];
    }
    __syncthreads();
#pragma unroll
    for (int r = 0; r < 16; ++r) {
        int srow = grp * 16 + r;
        xt[(s0 + srow) * 64 + lane] = __bfloat16_as_ushort(__float2bfloat16(tile[lane][srow]));
    }
}

// ---- prep 2: weight [o][c][k] f32 -> A-fragments wf[k][i=ot*2+kb][lane][e] bf16 ----
__global__ void prep_w_frag(const float* __restrict__ w, unsigned short* __restrict__ wt) {
    int idx = blockIdx.x * 256 + threadIdx.x;
    if (idx >= KPROD * 4096) return;
    int k = idx >> 12;
    int fid = idx & 4095;
    int i = fid >> 9;                 // ot*2+kb
    int lane = (fid >> 3) & 63;
    int e = fid & 7;
    int ot = i >> 1, kb = i & 1;
    int o = ot * 16 + (lane & 15);
    int c = kb * 32 + (lane >> 4) * 8 + e;
    wt[idx] = __bfloat16_as_ushort(__float2bfloat16(w[(o * 64 + c) * KPROD + k]));
}

// ---- main: one wave per 16 output positions, zero barriers ----
__global__ __launch_bounds__(64)
void dconv3d_wave(const unsigned short* __restrict__ xt, const unsigned short* __restrict__ wf,
                  const float* __restrict__ offset, const float* __restrict__ mask,
                  float* __restrict__ out) {
    __shared__ float meta_w[2][8][24];   // stride 24: 2-way max bank aliasing
    __shared__ int   meta_o[2][8][24];

    const int l = threadIdx.x;
    const int pl = l & 15;               // my output position (within tile)
    const int g  = l >> 4;               // quad group / k-slice
    const int g16 = g * 16;
    const int pos = blockIdx.x * 16 + pl;
    const int ho = pos >> 10, wo = (pos >> 5) & 31, lo = pos & 31;
    const char* xbase = (const char*)xt;

    f32x4 acc[4] = {};

    auto compute_meta = [&](int k, int buf) {
        float oh = offset[(3 * k + 0) * SPAT + pos];
        float ow = offset[(3 * k + 1) * SPAT + pos];
        float ol = offset[(3 * k + 2) * SPAT + pos];
        float mk = mask[k * SPAT + pos];
        int ki = k / 9, kj = (k / 3) % 3, kk = k % 3;
        float chh = oh + (float)(ho - 1 + ki);
        float cww = ow + (float)(wo - 1 + kj);
        float cll = ol + (float)(lo - 1 + kk);
        float h0f = floorf(chh), w0f = floorf(cww), l0f = floorf(cll);
        float fh = chh - h0f, fw = cww - w0f, fl = cll - l0f;
        int h0 = (int)h0f, w0 = (int)w0f, l0i = (int)l0f;
#pragma unroll
        for (int jj = 0; jj < 2; ++jj) {
            int j = g * 2 + jj;          // this lane owns 2 corners of its p
            int dh = j >> 2, dw = (j >> 1) & 1, dl = j & 1;
            int ih = h0 + dh, iw = w0 + dw, il = l0i + dl;
            float wh = dh ? fh : 1.f - fh;
            float ww = dw ? fw : 1.f - fw;
            float wl = dl ? fl : 1.f - fl;
            bool valid = (unsigned)ih < 32u && (unsigned)iw < 32u && (unsigned)il < 32u;
            float wvv = valid ? wh * ww * wl * mk : 0.f;
            int ihc = min(max(ih, 0), 31);
            int iwc = min(max(iw, 0), 31);
            int ilc = min(max(il, 0), 31);
            int lin = (ihc * 32 + iwc) * 32 + ilc;
            meta_w[buf][j][pl] = wvv;
            meta_o[buf][j][pl] = lin * 128;   // byte offset of bf16 row
        }
    };

    // ---- prologue: meta(0) + W-frags(0) ----
    compute_meta(0, 0);
    float mw[8]; int mo[8];
#pragma unroll
    for (int j = 0; j < 8; ++j) { mw[j] = meta_w[0][j][pl]; mo[j] = meta_o[0][j][pl]; }
    short8 wfr[8];
#pragma unroll
    for (int i = 0; i < 8; ++i) wfr[i] = *(const short8*)&wf[(size_t)i * 512 + l * 8];

#pragma unroll 1
    for (int k = 0; k < KPROD; ++k) {
        const int kn = (k + 1 < KPROD) ? k + 1 : k;
        const int bufn = (k + 1) & 1;

        // 1. issue all 16 gathers for tap k (bf16 octets = my B-fragment slices)
        u32x4 q0[8], q1[8];
#pragma unroll
        for (int j = 0; j < 8; ++j) {
            const char* rowp = xbase + (mo[j] + g16);
            q0[j] = *(const u32x4*)rowp;          // c-octet, kb=0
            q1[j] = *(const u32x4*)(rowp + 64);   // c-octet, kb=1
        }

        // 2. overlap: meta for tap k+1 (global loads + VALU + LDS writes)
        compute_meta(kn, bufn);

        // 3. consume gathers: trilinear accumulate in f32
        float v0[8] = {0.f,0.f,0.f,0.f,0.f,0.f,0.f,0.f};
        float v1[8] = {0.f,0.f,0.f,0.f,0.f,0.f,0.f,0.f};
#pragma unroll
        for (int j = 0; j < 8; ++j) {
            float w = mw[j];
#pragma unroll
            for (int q = 0; q < 4; ++q) {
                v0[2*q]   = fmaf(w, __uint_as_float(q0[j][q] << 16), v0[2*q]);
                v0[2*q+1] = fmaf(w, __uint_as_float(q0[j][q] & 0xffff0000u), v0[2*q+1]);
                v1[2*q]   = fmaf(w, __uint_as_float(q1[j][q] << 16), v1[2*q]);
                v1[2*q+1] = fmaf(w, __uint_as_float(q1[j][q] & 0xffff0000u), v1[2*q+1]);
            }
        }

        // 4. B-fragments (bf16)
        short8 b0, b1;
#pragma unroll
        for (int e = 0; e < 8; ++e) {
            b0[e] = (short)__bfloat16_as_ushort(__float2bfloat16(v0[e]));
            b1[e] = (short)__bfloat16_as_ushort(__float2bfloat16(v1[e]));
        }

        // 5. prefetch W-frags for k+1 (q regs are dead now)
        short8 wfn[8];
#pragma unroll
        for (int i = 0; i < 8; ++i) wfn[i] = *(const short8*)&wf[((size_t)kn * 8 + i) * 512 + l * 8];

        // 6. MFMA: 64o x 16p, K=64
#pragma unroll
        for (int ot = 0; ot < 4; ++ot) {
            acc[ot] = __builtin_amdgcn_mfma_f32_16x16x32_bf16(wfr[ot*2+0], b0, acc[ot], 0, 0, 0);
            acc[ot] = __builtin_amdgcn_mfma_f32_16x16x32_bf16(wfr[ot*2+1], b1, acc[ot], 0, 0, 0);
        }

        // 7. pull meta(k+1) into regs; rotate W
#pragma unroll
        for (int j = 0; j < 8; ++j) { mw[j] = meta_w[bufn][j][pl]; mo[j] = meta_o[bufn][j][pl]; }
#pragma unroll
        for (int i = 0; i < 8; ++i) wfr[i] = wfn[i];
    }

    // ---- store: D col=lane&15 (p), row=g*4+r (o) ----
#pragma unroll
    for (int ot = 0; ot < 4; ++ot)
#pragma unroll
        for (int r = 0; r < 4; ++r) {
            int o = ot * 16 + g * 4 + r;
            out[(size_t)o * SPAT + pos] = acc[ot][r];
        }
}

extern "C" void kernel_launch(void* const* d_in, const int* in_sizes, int n_in,
                              void* d_out, int out_size, void* d_ws, size_t ws_size,
                              hipStream_t stream) {
    const float* x      = (const float*)d_in[0];
    const float* offset = (const float*)d_in[1];
    const float* mask   = (const float*)d_in[2];
    const float* weight = (const float*)d_in[3];
    float* out = (float*)d_out;

    unsigned short* xt  = (unsigned short*)d_ws;                              // 4 MB
    unsigned short* wtb = (unsigned short*)((char*)d_ws + (size_t)SPAT * 64 * 2); // 216 KB

    hipLaunchKernelGGL(transpose_x_bf16, dim3(SPAT / 64), dim3(256), 0, stream, x, xt);
    hipLaunchKernelGGL(prep_w_frag, dim3((KPROD * 4096 + 255) / 256), dim3(256), 0, stream,
                       weight, wtb);
    hipLaunchKernelGGL(dconv3d_wave, dim3(SPAT / 16), dim3(64), 0, stream,
                       xt, wtb, offset, mask, out);
}